// Round 16
// baseline (652.089 us; speedup 1.0000x reference)
//
#include <hip/hip_runtime.h>
#include <hip/hip_bf16.h>
#include <math.h>

#define Bb 4
#define Nn 2048
#define Kk 32
#define Hh 128
#define NIi 256
#define NH_ 4
#define Dd 32
#define DFFh 512

#define NEGF -3.402823466e38f

typedef unsigned short u16;
typedef __attribute__((ext_vector_type(8))) short bf16x8;
typedef __attribute__((ext_vector_type(4))) short s16x4;
typedef __attribute__((ext_vector_type(4))) float f32x4;

// bf16 weight buffer offsets (elements); base = d_ws + 2MB
#define OFF_NAWKT   0        // [128][256]
#define OFF_NAWVT   32768    // [128][256]
#define OFF_EAWKT   65536    // [128][128]
#define OFF_EAWVT   81920
#define OFF_EAWOT   98304
#define OFF_D2WINT  114688   // [512][128]
#define OFF_D2WOUTT 180224   // [128][512]
#define OFF_OPW2T   245760   // [128][128]
#define OFF_D1WINT  262144   // [512][128]
#define OFF_D1WOUTT 327680   // [128][512]
#define OFF_OPW1T   393216   // [128][128]
#define OFF_NAWQT   409600   // [128][128]
#define OFF_NAWOT   425984   // [128][128]
#define WB_TOTAL    442368

// Fast exact-gelu: A&S 7.1.26 erf (|eps|<=1.5e-7), branchless.
__device__ __forceinline__ float gelu_f(float x) {
    float z = x * 0.7071067811865476f;
    float a = fabsf(z);
    float d = fmaf(0.3275911f, a, 1.0f);
    float t = __fdividef(1.0f, d);
    float p = fmaf(fmaf(fmaf(fmaf(1.061405429f, t, -1.453152027f), t,
                             1.421413741f), t, -0.284496736f), t, 0.254829592f);
    float e = __expf(-a * a);
    float erfa = fmaf(-p * t, e, 1.0f);
    float er = copysignf(erfa, z);
    return 0.5f * x * (1.0f + er);
}

__device__ __forceinline__ u16 f2bf(float f) {
    union { __hip_bfloat16 h; u16 u; } v;
    v.h = __float2bfloat16(f);
    return v.u;
}

__device__ __forceinline__ float bf2f(u16 u) {
    union { unsigned int u; float f; } v; v.u = ((unsigned int)u) << 16;
    return v.f;
}

__device__ __forceinline__ s16x4 packbf4(f32x4 v) {
    s16x4 r;
    r.x = (short)f2bf(v.x); r.y = (short)f2bf(v.y);
    r.z = (short)f2bf(v.z); r.w = (short)f2bf(v.w);
    return r;
}

// ---------------- K0: convert + transpose weights to bf16 in ws ---------------
__global__ __launch_bounds__(256) void k_prep(
    const float* __restrict__ naWK, const float* __restrict__ naWV,
    const float* __restrict__ eaWK, const float* __restrict__ eaWV,
    const float* __restrict__ eaWO, const float* __restrict__ d2Win,
    const float* __restrict__ d2Wout, const float* __restrict__ opW2,
    const float* __restrict__ d1Win, const float* __restrict__ d1Wout,
    const float* __restrict__ opW1, const float* __restrict__ naWQ,
    const float* __restrict__ naWO, u16* __restrict__ wb)
{
    int i = blockIdx.x * 256 + threadIdx.x;
    const float* src; int R, C, off;
    if (i < 32768)       { src = naWK;   R = 256; C = 128; off = OFF_NAWKT; }
    else if (i < 65536)  { src = naWV;   R = 256; C = 128; off = OFF_NAWVT; }
    else if (i < 81920)  { src = eaWK;   R = 128; C = 128; off = OFF_EAWKT; }
    else if (i < 98304)  { src = eaWV;   R = 128; C = 128; off = OFF_EAWVT; }
    else if (i < 114688) { src = eaWO;   R = 128; C = 128; off = OFF_EAWOT; }
    else if (i < 180224) { src = d2Win;  R = 128; C = 512; off = OFF_D2WINT; }
    else if (i < 245760) { src = d2Wout; R = 512; C = 128; off = OFF_D2WOUTT; }
    else if (i < 262144) { src = opW2;   R = 128; C = 128; off = OFF_OPW2T; }
    else if (i < 327680) { src = d1Win;  R = 128; C = 512; off = OFF_D1WINT; }
    else if (i < 393216) { src = d1Wout; R = 512; C = 128; off = OFF_D1WOUTT; }
    else if (i < 409600) { src = opW1;   R = 128; C = 128; off = OFF_OPW1T; }
    else if (i < 425984) { src = naWQ;   R = 128; C = 128; off = OFF_NAWQT; }
    else                 { src = naWO;   R = 128; C = 128; off = OFF_NAWOT; }
    int j = i - off;
    int c = j / R, r = j - c * R;       // dest W^T[C][R]
    wb[i] = f2bf(src[r * C + c]);
}

// ---------------- K1a: batched Qall = hV @ WQ (bf16) --------------------------
__global__ __launch_bounds__(256) void k_qproj(
    const float* __restrict__ hV, const u16* __restrict__ wb,
    u16* __restrict__ Qall)
{
    __shared__ __align__(16) short A1[32 * 136];
    const int bn = blockIdx.x, t = threadIdx.x;
    const int w = t >> 6, l = t & 63, l15 = l & 15, lq = l >> 4;
    const float* xp = hV + (size_t)bn * 4096;
    for (int i4 = t * 4; i4 < 4096; i4 += 1024)
        *(s16x4*)&A1[(i4 >> 7) * 136 + (i4 & 127)] = packbf4(*(const f32x4*)&xp[i4]);
    __syncthreads();
    #pragma unroll
    for (int ni = 0; ni < 2; ++ni) {
        int n0 = (w + 4 * ni) * 16;
        f32x4 acc0 = {0.f, 0.f, 0.f, 0.f}, acc1 = {0.f, 0.f, 0.f, 0.f};
        __builtin_amdgcn_s_setprio(1);
        #pragma unroll
        for (int kt = 0; kt < 4; ++kt) {
            bf16x8 wf = *(const bf16x8*)(wb + OFF_NAWQT + (size_t)(n0 + l15) * 128 + kt * 32 + lq * 8);
            bf16x8 a0 = *(const bf16x8*)&A1[(l15) * 136 + kt * 32 + lq * 8];
            bf16x8 a1 = *(const bf16x8*)&A1[(16 + l15) * 136 + kt * 32 + lq * 8];
            acc0 = __builtin_amdgcn_mfma_f32_16x16x32_bf16(a0, wf, acc0, 0, 0, 0);
            acc1 = __builtin_amdgcn_mfma_f32_16x16x32_bf16(a1, wf, acc1, 0, 0, 0);
        }
        __builtin_amdgcn_s_setprio(0);
        int col = n0 + l15;
        #pragma unroll
        for (int r = 0; r < 4; ++r) {
            Qall[(size_t)(bn * 32 + lq * 4 + r) * 128 + col] = f2bf(acc0[r]);
            Qall[(size_t)(bn * 32 + 16 + lq * 4 + r) * 128 + col] = f2bf(acc1[r]);
        }
    }
}

// ---------------- K1b: per-token attention core -> outr (bf16) ----------------
__global__ __launch_bounds__(256, 4) void k_node_core(
    const float* __restrict__ hEV, const float* __restrict__ maskA,
    const u16* __restrict__ Qall, const u16* __restrict__ wb,
    u16* __restrict__ outr)
{
    __shared__ __align__(16) short EVb[32 * 264];   // 16.9 KB
    __shared__ __align__(16) short KtT[128 * 36];   // K^T [h][k], 9.2 KB
    __shared__ __align__(16) short VtT[128 * 36];   // V^T [h][k], 9.2 KB
    __shared__ float Qs[128];
    __shared__ float att[NH_][Kk];

    const int bn = blockIdx.x, t = threadIdx.x;
    const int w = t >> 6, l = t & 63, l15 = l & 15, lq = l >> 4;
    const float* evp = hEV + (size_t)bn * 8192;
    for (int i8 = t * 8; i8 < 8192; i8 += 2048) {
        f32x4 v0 = *(const f32x4*)&evp[i8];
        f32x4 v1 = *(const f32x4*)&evp[i8 + 4];
        int r = i8 >> 8, c = i8 & 255;
        *(s16x4*)&EVb[r * 264 + c] = packbf4(v0);
        *(s16x4*)&EVb[r * 264 + c + 4] = packbf4(v1);
    }
    if (t < 128) Qs[t] = bf2f(Qall[(size_t)bn * 128 + t]);
    __syncthreads();

    // K = EV @ WK, V = EV @ WV; weight frag shared across both m-tiles
    #pragma unroll
    for (int i = 0; i < 4; ++i) {
        int pair = w + 4 * i;            // 0..15: mat = pair>>3, n = pair&7
        int mat = pair >> 3, n0 = (pair & 7) << 4;
        const u16* Bp = wb + (mat ? OFF_NAWVT : OFF_NAWKT);
        f32x4 acc0 = {0.f, 0.f, 0.f, 0.f}, acc1 = {0.f, 0.f, 0.f, 0.f};
        __builtin_amdgcn_s_setprio(1);
        #pragma unroll
        for (int kt = 0; kt < 8; ++kt) {
            bf16x8 wf = *(const bf16x8*)(Bp + (size_t)(n0 + l15) * 256 + kt * 32 + lq * 8);
            bf16x8 a0 = *(const bf16x8*)&EVb[(l15) * 264 + kt * 32 + lq * 8];
            bf16x8 a1 = *(const bf16x8*)&EVb[(16 + l15) * 264 + kt * 32 + lq * 8];
            acc0 = __builtin_amdgcn_mfma_f32_16x16x32_bf16(a0, wf, acc0, 0, 0, 0);
            acc1 = __builtin_amdgcn_mfma_f32_16x16x32_bf16(a1, wf, acc1, 0, 0, 0);
        }
        __builtin_amdgcn_s_setprio(0);
        int col = n0 + l15;
        short* dst = mat ? VtT : KtT;
        *(s16x4*)&dst[col * 36 + lq * 4] = packbf4(acc0);
        *(s16x4*)&dst[col * 36 + 16 + lq * 4] = packbf4(acc1);
    }
    __syncthreads();

    if (t < 128) {
        int nh = t >> 5, k = t & 31;
        float a = 0.f;
        #pragma unroll
        for (int d = 0; d < 32; ++d)
            a += Qs[nh * 32 + d] * bf2f(KtT[(nh * 32 + d) * 36 + k]);
        float mk = maskA[(size_t)bn * 32 + k];
        float lg = (mk > 0.f) ? a * 0.17677669529663687f : NEGF;
        float mx = lg;
        #pragma unroll
        for (int s = 16; s; s >>= 1) mx = fmaxf(mx, __shfl_xor(mx, s, 32));
        float e = __expf(lg - mx);
        float sum = e;
        #pragma unroll
        for (int s = 16; s; s >>= 1) sum += __shfl_xor(sum, s, 32);
        att[nh][k] = mk * e / sum;
    }
    __syncthreads();
    if (t < 128) {
        int nh = t >> 5, d = t & 31;
        float a = 0.f;
        #pragma unroll
        for (int k = 0; k < 32; ++k)
            a += att[nh][k] * bf2f(VtT[(nh * 32 + d) * 36 + k]);
        outr[(size_t)bn * 128 + t] = f2bf(a);
    }
}

// ---------------- K1c: fused node post: WO+LN1 -> FFN+LN1+mask -> LNop@W1 -----
__global__ __launch_bounds__(256, 3) void k_node_post(
    const u16* __restrict__ outr, const float* __restrict__ hV,
    const u16* __restrict__ wb, const float* __restrict__ maskV,
    const float* __restrict__ n1g, const float* __restrict__ n1b,
    const float* __restrict__ bin, const float* __restrict__ bout,
    const float* __restrict__ b1, const float* __restrict__ opg,
    const float* __restrict__ opb,
    float* __restrict__ outV, u16* __restrict__ xop)
{
    __shared__ __align__(16) float Xf[32][132];
    __shared__ __align__(16) short A1[32 * 136];
    __shared__ __align__(16) short Hd[32 * 264];
    __shared__ float mu_[32], isd_[32];
    const int bn = blockIdx.x, t = threadIdx.x;
    const int w = t >> 6, l = t & 63, l15 = l & 15, lq = l >> 4;
    const float* xp = hV + (size_t)bn * 4096;
    const u16* op = outr + (size_t)bn * 4096;
    for (int i4 = t * 4; i4 < 4096; i4 += 1024) {
        int r = i4 >> 7, c = i4 & 127;
        *(f32x4*)&Xf[r][c] = *(const f32x4*)&xp[i4];
        *(s16x4*)&A1[r * 136 + c] = *(const s16x4*)&op[i4];
    }
    __syncthreads();
    // WO gemm + gelu + residual (weight shared across both m-tiles)
    #pragma unroll
    for (int ni = 0; ni < 2; ++ni) {
        int n0 = (w + 4 * ni) * 16;
        f32x4 acc0 = {0.f, 0.f, 0.f, 0.f}, acc1 = {0.f, 0.f, 0.f, 0.f};
        __builtin_amdgcn_s_setprio(1);
        #pragma unroll
        for (int kt = 0; kt < 4; ++kt) {
            bf16x8 wf = *(const bf16x8*)(wb + OFF_NAWOT + (size_t)(n0 + l15) * 128 + kt * 32 + lq * 8);
            bf16x8 a0 = *(const bf16x8*)&A1[(l15) * 136 + kt * 32 + lq * 8];
            bf16x8 a1 = *(const bf16x8*)&A1[(16 + l15) * 136 + kt * 32 + lq * 8];
            acc0 = __builtin_amdgcn_mfma_f32_16x16x32_bf16(a0, wf, acc0, 0, 0, 0);
            acc1 = __builtin_amdgcn_mfma_f32_16x16x32_bf16(a1, wf, acc1, 0, 0, 0);
        }
        __builtin_amdgcn_s_setprio(0);
        int col = n0 + l15;
        #pragma unroll
        for (int r = 0; r < 4; ++r) {
            Xf[lq * 4 + r][col] += gelu_f(acc0[r]);
            Xf[16 + lq * 4 + r][col] += gelu_f(acc1[r]);
        }
    }
    __syncthreads();
    // LN1 stats
    {
        int r = t >> 3, sub = t & 7;
        float s = 0.f, ss = 0.f;
        #pragma unroll
        for (int j = 0; j < 16; ++j) { float v = Xf[r][sub * 16 + j]; s += v; ss += v * v; }
        #pragma unroll
        for (int m = 1; m < 8; m <<= 1) { s += __shfl_xor(s, m, 8); ss += __shfl_xor(ss, m, 8); }
        if (sub == 0) {
            float mu = s * (1.f / 128.f);
            mu_[r] = mu;
            isd_[r] = 1.f / sqrtf(ss * (1.f / 128.f) - mu * mu + 1e-5f);
        }
    }
    __syncthreads();
    // apply LN1 -> Xf fp32 + A1 bf16 (FFN input)
    for (int i4 = t * 4; i4 < 4096; i4 += 1024) {
        int r = i4 >> 7, c = i4 & 127;
        f32x4 xv = *(const f32x4*)&Xf[r][c];
        f32x4 y;
        #pragma unroll
        for (int j = 0; j < 4; ++j)
            y[j] = n1g[c + j] * (xv[j] - mu_[r]) * isd_[r] + n1b[c + j];
        *(f32x4*)&Xf[r][c] = y;
        *(s16x4*)&A1[r * 136 + c] = packbf4(y);
    }
    __syncthreads();

    // FFN
    bf16x8 aA[2][4];
    #pragma unroll
    for (int m = 0; m < 2; ++m)
        #pragma unroll
        for (int kt = 0; kt < 4; ++kt)
            aA[m][kt] = *(const bf16x8*)&A1[(m * 16 + l15) * 136 + kt * 32 + lq * 8];

    const int col0 = w * 16 + l15, col1 = (w + 4) * 16 + l15;
    f32x4 acc2[2][2];
    #pragma unroll
    for (int i = 0; i < 2; ++i)
        #pragma unroll
        for (int m = 0; m < 2; ++m) acc2[i][m] = (f32x4){0.f, 0.f, 0.f, 0.f};

    for (int ch = 0; ch < 2; ++ch) {
        #pragma unroll
        for (int nt = 0; nt < 4; ++nt) {
            int n0c = (w * 4 + nt) * 16;
            int g0 = ch * 256 + n0c;
            f32x4 bi4 = *(const f32x4*)&bin[g0 + lq * 4];
            f32x4 accp[2];
            __builtin_amdgcn_s_setprio(1);
            #pragma unroll
            for (int m = 0; m < 2; ++m) {
                f32x4 acc = {0.f, 0.f, 0.f, 0.f};
                #pragma unroll
                for (int kt = 0; kt < 4; ++kt) {
                    bf16x8 wA = *(const bf16x8*)(wb + OFF_D1WINT + (size_t)(g0 + l15) * 128 + kt * 32 + lq * 8);
                    acc = __builtin_amdgcn_mfma_f32_16x16x32_bf16(wA, aA[m][kt], acc, 0, 0, 0);
                }
                accp[m] = acc;
            }
            __builtin_amdgcn_s_setprio(0);
            #pragma unroll
            for (int m = 0; m < 2; ++m) {
                f32x4 g;
                #pragma unroll
                for (int r = 0; r < 4; ++r) g[r] = gelu_f(accp[m][r] + bi4[r]);
                *(s16x4*)&Hd[(m * 16 + l15) * 264 + n0c + lq * 4] = packbf4(g);
            }
        }
        __syncthreads();
        __builtin_amdgcn_s_setprio(1);
        #pragma unroll
        for (int kt = 0; kt < 8; ++kt) {
            bf16x8 a0 = *(const bf16x8*)&Hd[l15 * 264 + kt * 32 + lq * 8];
            bf16x8 a1 = *(const bf16x8*)&Hd[(16 + l15) * 264 + kt * 32 + lq * 8];
            bf16x8 b0 = *(const bf16x8*)(wb + OFF_D1WOUTT + (size_t)col0 * 512 + ch * 256 + kt * 32 + lq * 8);
            bf16x8 b1 = *(const bf16x8*)(wb + OFF_D1WOUTT + (size_t)col1 * 512 + ch * 256 + kt * 32 + lq * 8);
            acc2[0][0] = __builtin_amdgcn_mfma_f32_16x16x32_bf16(a0, b0, acc2[0][0], 0, 0, 0);
            acc2[0][1] = __builtin_amdgcn_mfma_f32_16x16x32_bf16(a1, b0, acc2[0][1], 0, 0, 0);
            acc2[1][0] = __builtin_amdgcn_mfma_f32_16x16x32_bf16(a0, b1, acc2[1][0], 0, 0, 0);
            acc2[1][1] = __builtin_amdgcn_mfma_f32_16x16x32_bf16(a1, b1, acc2[1][1], 0, 0, 0);
        }
        __builtin_amdgcn_s_setprio(0);
        __syncthreads();
    }
    #pragma unroll
    for (int ni = 0; ni < 2; ++ni) {
        int col = ni ? col1 : col0;
        float bo = bout[col];
        #pragma unroll
        for (int m = 0; m < 2; ++m)
            #pragma unroll
            for (int r = 0; r < 4; ++r)
                Xf[m * 16 + lq * 4 + r][col] += gelu_f(acc2[ni][m][r] + bo);
    }
    __syncthreads();
    // LN1 #2 stats
    {
        int r = t >> 3, sub = t & 7;
        float s = 0.f, ss = 0.f;
        #pragma unroll
        for (int j = 0; j < 16; ++j) { float v = Xf[r][sub * 16 + j]; s += v; ss += v * v; }
        #pragma unroll
        for (int m = 1; m < 8; m <<= 1) { s += __shfl_xor(s, m, 8); ss += __shfl_xor(ss, m, 8); }
        if (sub == 0) {
            float mu = s * (1.f / 128.f);
            mu_[r] = mu;
            isd_[r] = 1.f / sqrtf(ss * (1.f / 128.f) - mu * mu + 1e-5f);
        }
    }
    __syncthreads();
    // apply LN1 + mask -> outV global + Xf (becomes hv2)
    float* ov = outV + (size_t)bn * 4096;
    for (int i4 = t * 4; i4 < 4096; i4 += 1024) {
        int r = i4 >> 7, c = i4 & 127;
        float mv = maskV[bn * 32 + r];
        f32x4 xv = *(const f32x4*)&Xf[r][c];
        f32x4 o;
        #pragma unroll
        for (int j = 0; j < 4; ++j)
            o[j] = mv * (n1g[c + j] * (xv[j] - mu_[r]) * isd_[r] + n1b[c + j]);
        *(f32x4*)&Xf[r][c] = o;
        *(f32x4*)&ov[i4] = o;
    }
    __syncthreads();
    // LN op stats
    {
        int r = t >> 3, sub = t & 7;
        float s = 0.f, ss = 0.f;
        #pragma unroll
        for (int j = 0; j < 16; ++j) { float v = Xf[r][sub * 16 + j]; s += v; ss += v * v; }
        #pragma unroll
        for (int m = 1; m < 8; m <<= 1) { s += __shfl_xor(s, m, 8); ss += __shfl_xor(ss, m, 8); }
        if (sub == 0) {
            float mu = s * (1.f / 128.f);
            mu_[r] = mu;
            isd_[r] = 1.f / sqrtf(ss * (1.f / 128.f) - mu * mu + 1e-5f);
        }
    }
    __syncthreads();
    for (int i4 = t * 4; i4 < 4096; i4 += 1024) {
        int r = i4 >> 7, c = i4 & 127;
        f32x4 xv = *(const f32x4*)&Xf[r][c];
        f32x4 y;
        #pragma unroll
        for (int j = 0; j < 4; ++j)
            y[j] = opg[c + j] * (xv[j] - mu_[r]) * isd_[r] + opb[c + j];
        *(s16x4*)&A1[r * 136 + c] = packbf4(y);
    }
    __syncthreads();
    // W1 gemm -> xop bf16 (weight shared across both m-tiles)
    #pragma unroll
    for (int ni = 0; ni < 2; ++ni) {
        int n0 = (w + 4 * ni) * 16;
        f32x4 acc0 = {0.f, 0.f, 0.f, 0.f}, acc1 = {0.f, 0.f, 0.f, 0.f};
        __builtin_amdgcn_s_setprio(1);
        #pragma unroll
        for (int kt = 0; kt < 4; ++kt) {
            bf16x8 wf = *(const bf16x8*)(wb + OFF_OPW1T + (size_t)(n0 + l15) * 128 + kt * 32 + lq * 8);
            bf16x8 a0 = *(const bf16x8*)&A1[(l15) * 136 + kt * 32 + lq * 8];
            bf16x8 a1 = *(const bf16x8*)&A1[(16 + l15) * 136 + kt * 32 + lq * 8];
            acc0 = __builtin_amdgcn_mfma_f32_16x16x32_bf16(a0, wf, acc0, 0, 0, 0);
            acc1 = __builtin_amdgcn_mfma_f32_16x16x32_bf16(a1, wf, acc1, 0, 0, 0);
        }
        __builtin_amdgcn_s_setprio(0);
        int col = n0 + l15;
        float bb = b1[col];
        #pragma unroll
        for (int r = 0; r < 4; ++r) {
            xop[(size_t)(bn * 32 + lq * 4 + r) * 128 + col] = f2bf(acc0[r] + bb);
            xop[(size_t)(bn * 32 + 16 + lq * 4 + r) * 128 + col] = f2bf(acc1[r] + bb);
        }
    }
}

// ---------------- K4: fused edge pipeline (r15 + packed Q/K/O2 writes) --------
#define LS_A 0
#define LS_B 9216
#define LS_C 17920
#define LS_D 26624
#define LS_SM 35840
__global__ __launch_bounds__(256, 4) void k_edge_fused(
    const u16* __restrict__ xop, const float* __restrict__ hE,
    const int* __restrict__ Eidx, const float* __restrict__ maskA,
    const u16* __restrict__ wb, const float* __restrict__ b2,
    const float* __restrict__ n3g, const float* __restrict__ n3b,
    const float* __restrict__ bin, const float* __restrict__ bout,
    const float* __restrict__ n4g, const float* __restrict__ n4b,
    float* __restrict__ outE)
{
    __shared__ __align__(16) char smem[37888];
    short* A1  = (short*)(smem + LS_A);
    short* Qe  = (short*)(smem + LS_B);
    short* Ke  = (short*)(smem + LS_C);
    short* Vp  = (short*)(smem + LS_D);
    short* Ls  = (short*)(smem + LS_A);        // bf16 logits/P [128][34]
    short* O2  = (short*)(smem + LS_B);        // attn out [32][136]
    short* Hd  = (short*)(smem + LS_B);        // FFN hidden [32][264]
    float* ms  = (float*)(smem + LS_SM);       // [32]
    float* mu_ = (float*)(smem + LS_SM + 128);
    float* isd_= (float*)(smem + LS_SM + 256);
    float* pps = (float*)(smem + LS_SM + 384); // [128]
    float* ppss= (float*)(smem + LS_SM + 896); // [128]
    float* xcf = (float*)(smem + LS_SM + 1408);// [128]
    int*   idxs= (int*)(smem + LS_SM + 1920);  // [32]

    const int bn = blockIdx.x, t = threadIdx.x;
    const int b = bn >> 11;
    const int w = t >> 6, l = t & 63, l15 = l & 15, lq = l >> 4;
    const int c0 = w * 16 + l15, c1 = c0 + 64;

    // phase 0: bases + per-col constants (hE loaded inline in phase 2a)
    if (t < 128) xcf[t] = bf2f(xop[(size_t)bn * 128 + t]);
    if (t < 32) { idxs[t] = Eidx[(size_t)bn * 32 + t]; ms[t] = maskA[(size_t)bn * 32 + t]; }
    const float bb_0 = b2[c0], bb_1 = b2[c1];
    const float g3_0 = n3g[c0], g3_1 = n3g[c1], b3_0 = n3b[c0], b3_1 = n3b[c1];
    const float g4_0 = n4g[c0], g4_1 = n4g[c1], b4_0 = n4b[c0], b4_1 = n4b[c1];
    const float bo_0 = bout[c0], bo_1 = bout[c1];
    __syncthreads();

    // phase 1: A = bf16(x ⊙ x[nbr])
    for (int i4 = t * 4; i4 < 4096; i4 += 1024) {
        int k = i4 >> 7, h = i4 & 127;
        s16x4 nb = *(const s16x4*)&xop[((size_t)b * Nn + idxs[k]) * 128 + h];
        f32x4 prod;
        prod.x = xcf[h] * bf2f(nb.x);
        prod.y = xcf[h + 1] * bf2f(nb.y);
        prod.z = xcf[h + 2] * bf2f(nb.z);
        prod.w = xcf[h + 3] * bf2f(nb.w);
        *(s16x4*)&A1[k * 136 + h] = packbf4(prod);
    }
    __syncthreads();

    // phase 2a: xv = hE + outer@W2 + b2  (weight shared across m; hE inline)
    float xv[4][4];
    #pragma unroll
    for (int ni = 0; ni < 2; ++ni) {
        int n0 = (w + 4 * ni) * 16;
        f32x4 acc0 = {0.f, 0.f, 0.f, 0.f}, acc1 = {0.f, 0.f, 0.f, 0.f};
        __builtin_amdgcn_s_setprio(1);
        #pragma unroll
        for (int kt = 0; kt < 4; ++kt) {
            bf16x8 wf = *(const bf16x8*)(wb + OFF_OPW2T + (size_t)(n0 + l15) * 128 + kt * 32 + lq * 8);
            bf16x8 a0 = *(const bf16x8*)&A1[(l15) * 136 + kt * 32 + lq * 8];
            bf16x8 a1 = *(const bf16x8*)&A1[(16 + l15) * 136 + kt * 32 + lq * 8];
            acc0 = __builtin_amdgcn_mfma_f32_16x16x32_bf16(a0, wf, acc0, 0, 0, 0);
            acc1 = __builtin_amdgcn_mfma_f32_16x16x32_bf16(a1, wf, acc1, 0, 0, 0);
        }
        __builtin_amdgcn_s_setprio(0);
        int col = n0 + l15;
        float bb = ni ? bb_1 : bb_0;
        #pragma unroll
        for (int r = 0; r < 4; ++r) {
            xv[ni][r] = acc0[r] + bb + hE[(size_t)bn * 4096 + (lq * 4 + r) * 128 + col];
            xv[2 + ni][r] = acc1[r] + bb + hE[(size_t)bn * 4096 + (16 + lq * 4 + r) * 128 + col];
        }
    }
    __syncthreads();
    // phase 2b: A = bf16(xv)   (xv[i]: i = (m-tile)*2 + ni)
    #pragma unroll
    for (int i = 0; i < 4; ++i) {
        int m0 = (i >> 1) << 4, col = (i & 1) ? c1 : c0;
        #pragma unroll
        for (int r = 0; r < 4; ++r)
            A1[(m0 + lq * 4 + r) * 136 + col] = (short)f2bf(xv[i][r]);
    }
    __syncthreads();

    // phase 3: projections Q=X@WO, K=X@WK, V=X@WV (weight shared across m;
    // operand-swapped so lane's 4 outputs are consecutive CHANNELS at one edge
    // row -> packed b64 Q/K writes)
    #pragma unroll
    for (int i = 0; i < 6; ++i) {
        int pair = w + 4 * i;            // 0..23: mat = pair>>3, n = pair&7
        int mat = pair >> 3, n0 = (pair & 7) << 4;
        const u16* Bp = wb + ((mat == 0) ? OFF_EAWOT : (mat == 1) ? OFF_EAWKT : OFF_EAWVT);
        f32x4 acc0 = {0.f, 0.f, 0.f, 0.f}, acc1 = {0.f, 0.f, 0.f, 0.f};
        __builtin_amdgcn_s_setprio(1);
        #pragma unroll
        for (int kt = 0; kt < 4; ++kt) {
            bf16x8 wf = *(const bf16x8*)(Bp + (size_t)(n0 + l15) * 128 + kt * 32 + lq * 8);
            bf16x8 a0 = *(const bf16x8*)&A1[(l15) * 136 + kt * 32 + lq * 8];
            bf16x8 a1 = *(const bf16x8*)&A1[(16 + l15) * 136 + kt * 32 + lq * 8];
            acc0 = __builtin_amdgcn_mfma_f32_16x16x32_bf16(wf, a0, acc0, 0, 0, 0);
            acc1 = __builtin_amdgcn_mfma_f32_16x16x32_bf16(wf, a1, acc1, 0, 0, 0);
        }
        __builtin_amdgcn_s_setprio(0);
        // acc0: rows(lq*4+r)=channels n0+lq*4+r, cols(l15)=edges 0-15
        // acc1: same channels, edges 16-31
        if (mat == 0) {
            *(s16x4*)&Qe[(l15) * 136 + n0 + lq * 4] = packbf4(acc0);
            *(s16x4*)&Qe[(16 + l15) * 136 + n0 + lq * 4] = packbf4(acc1);
        } else if (mat == 1) {
            *(s16x4*)&Ke[(l15) * 136 + n0 + lq * 4] = packbf4(acc0);
            *(s16x4*)&Ke[(16 + l15) * 136 + n0 + lq * 4] = packbf4(acc1);
        } else {
            #pragma unroll
            for (int r = 0; r < 4; ++r) {
                int ch = n0 + lq * 4 + r;
                int e0 = l15, e1 = 16 + l15;
                Vp[((e0 >> 3) * 32 + (ch & 31)) * 34 + (((e0 & 7) << 2) | (ch >> 5))] =
                    (short)f2bf(acc0[r]);
                Vp[((e1 >> 3) * 32 + (ch & 31)) * 34 + (((e1 & 7) << 2) | (ch >> 5))] =
                    (short)f2bf(acc1[r]);
            }
        }
    }
    __syncthreads();

    // phase 4: logits via MFMA, bf16 written in swapped order into Ls (A region)
    #pragma unroll
    for (int i = 0; i < 4; ++i) {
        int id = w + 4 * i;
        int h = id >> 2, rem = id & 3;
        int q0 = (rem >> 1) << 4, k0 = (rem & 1) << 4;
        int q = q0 + l15, k = k0 + l15;
        bf16x8 a = *(const bf16x8*)&Qe[(((h << 3) | (q >> 2)) * 136) + (((q & 3) << 5) + lq * 8)];
        bf16x8 bv = *(const bf16x8*)&Ke[(((h << 3) | (k >> 2)) * 136) + (((k & 3) << 5) + lq * 8)];
        f32x4 z = {0.f, 0.f, 0.f, 0.f};
        __builtin_amdgcn_s_setprio(1);
        f32x4 acc = __builtin_amdgcn_mfma_f32_16x16x32_bf16(a, bv, z, 0, 0, 0);
        __builtin_amdgcn_s_setprio(0);
        int aa = l15 & 3;
        int kq = (k0 >> 2) + (l15 >> 2);
        int cc = (h << 3) + (q0 >> 2) + lq;
        #pragma unroll
        for (int r = 0; r < 4; ++r) {
            int q2 = (r << 3) | kq;
            Ls[(aa * 32 + q2) * 34 + cc] = (short)f2bf(acc[r] * 0.17677669529663687f);
        }
    }
    __syncthreads();

    // phase 5: masked softmax over c, 256 threads (pair splits the 32-c row)
    {
        int rr = t >> 1, hf = t & 1;
        int q2 = rr & 31;
        float mq = ms[q2];
        float lv[16];
        int base = rr * 34 + hf * 16;
        #pragma unroll
        for (int j = 0; j < 4; ++j) {
            s16x4 v = *(const s16x4*)&Ls[base + j * 4];
            lv[j * 4] = bf2f(v.x); lv[j * 4 + 1] = bf2f(v.y);
            lv[j * 4 + 2] = bf2f(v.z); lv[j * 4 + 3] = bf2f(v.w);
        }
        float mx = NEGF;
        #pragma unroll
        for (int c = 0; c < 16; ++c) {
            lv[c] = (mq * ms[hf * 16 + c] > 0.f) ? lv[c] : NEGF;
            mx = fmaxf(mx, lv[c]);
        }
        mx = fmaxf(mx, __shfl_xor(mx, 1));
        float s = 0.f;
        #pragma unroll
        for (int c = 0; c < 16; ++c) { lv[c] = __expf(lv[c] - mx); s += lv[c]; }
        s += __shfl_xor(s, 1);
        float inv = 1.f / s;
        #pragma unroll
        for (int j = 0; j < 4; ++j) {
            f32x4 pv;
            pv.x = lv[j * 4] * inv; pv.y = lv[j * 4 + 1] * inv;
            pv.z = lv[j * 4 + 2] * inv; pv.w = lv[j * 4 + 3] * inv;
            *(s16x4*)&Ls[base + j * 4] = packbf4(pv);
        }
    }
    __syncthreads();

    // phase 6: PV (swapped) -> O2 packed b64 (r8-verified pattern, stride 34)
    #pragma unroll
    for (int i = 0; i < 4; ++i) {
        int id = w + 4 * i;
        int a = id >> 2, rem = id & 3;
        int q0 = (rem >> 1) << 4, d0 = (rem & 1) << 4;
        bf16x8 pa = *(const bf16x8*)&Ls[((a * 32 + q0 + l15) * 34) + lq * 8];
        bf16x8 vb = *(const bf16x8*)&Vp[((a * 32 + d0 + l15) * 34) + lq * 8];
        f32x4 z = {0.f, 0.f, 0.f, 0.f};
        __builtin_amdgcn_s_setprio(1);
        f32x4 acc = __builtin_amdgcn_mfma_f32_16x16x32_bf16(vb, pa, z, 0, 0, 0);
        __builtin_amdgcn_s_setprio(0);
        *(s16x4*)&O2[(q0 + l15) * 136 + (a << 5) + d0 + lq * 4] = packbf4(acc);
    }
    __syncthreads();

    // phase 7: xv += gelu(O2 @ WO)  (weight shared across m)
    #pragma unroll
    for (int ni = 0; ni < 2; ++ni) {
        int n0 = (w + 4 * ni) * 16;
        f32x4 acc0 = {0.f, 0.f, 0.f, 0.f}, acc1 = {0.f, 0.f, 0.f, 0.f};
        __builtin_amdgcn_s_setprio(1);
        #pragma unroll
        for (int kt = 0; kt < 4; ++kt) {
            bf16x8 wf = *(const bf16x8*)(wb + OFF_EAWOT + (size_t)(n0 + l15) * 128 + kt * 32 + lq * 8);
            bf16x8 a0 = *(const bf16x8*)&O2[(l15) * 136 + kt * 32 + lq * 8];
            bf16x8 a1 = *(const bf16x8*)&O2[(16 + l15) * 136 + kt * 32 + lq * 8];
            acc0 = __builtin_amdgcn_mfma_f32_16x16x32_bf16(a0, wf, acc0, 0, 0, 0);
            acc1 = __builtin_amdgcn_mfma_f32_16x16x32_bf16(a1, wf, acc1, 0, 0, 0);
        }
        __builtin_amdgcn_s_setprio(0);
        #pragma unroll
        for (int r = 0; r < 4; ++r) {
            xv[ni][r] += gelu_f(acc0[r]);
            xv[2 + ni][r] += gelu_f(acc1[r]);
        }
    }
    __syncthreads();

    // phase 8: LN3 stats  (xv[i]: row block = (i>>1)*16, col = (i&1)?c1:c0)
    {
        float s8[8], ss8[8];
        #pragma unroll
        for (int j = 0; j < 8; ++j) { s8[j] = 0.f; ss8[j] = 0.f; }
        #pragma unroll
        for (int i = 0; i < 4; ++i)
            #pragma unroll
            for (int r = 0; r < 4; ++r) {
                int j = (i >> 1) * 4 + r;
                float v = xv[i][r];
                s8[j] += v; ss8[j] += v * v;
            }
        #pragma unroll
        for (int m = 1; m < 16; m <<= 1)
            #pragma unroll
            for (int j = 0; j < 8; ++j) {
                s8[j] += __shfl_xor(s8[j], m);
                ss8[j] += __shfl_xor(ss8[j], m);
            }
        if (l15 == 0) {
            #pragma unroll
            for (int j = 0; j < 8; ++j) {
                int row = (j >> 2) * 16 + lq * 4 + (j & 3);
                pps[w * 32 + row] = s8[j];
                ppss[w * 32 + row] = ss8[j];
            }
        }
    }
    __syncthreads();
    if (t < 32) {
        float s = pps[t] + pps[32 + t] + pps[64 + t] + pps[96 + t];
        float ss = ppss[t] + ppss[32 + t] + ppss[64 + t] + ppss[96 + t];
        float mu = s * (1.f / 128.f);
        mu_[t] = mu;
        isd_[t] = 1.f / sqrtf(ss * (1.f / 128.f) - mu * mu + 1e-5f);
    }
    __syncthreads();

    // phase 9: x2 = LN3(xv) -> regs + A region bf16 (Ls dead)
    #pragma unroll
    for (int i = 0; i < 4; ++i) {
        int m0 = (i >> 1) << 4, col = (i & 1) ? c1 : c0;
        float g = (i & 1) ? g3_1 : g3_0, bB = (i & 1) ? b3_1 : b3_0;
        #pragma unroll
        for (int r = 0; r < 4; ++r) {
            int row = m0 + lq * 4 + r;
            float v = g * (xv[i][r] - mu_[row]) * isd_[row] + bB;
            xv[i][r] = v;
            A1[row * 136 + col] = (short)f2bf(v);
        }
    }
    __syncthreads();

    // phase 10: FFN (Hd overlays B+C; weights already shared across m)
    bf16x8 aA[2][4];
    #pragma unroll
    for (int m = 0; m < 2; ++m)
        #pragma unroll
        for (int kt = 0; kt < 4; ++kt)
            aA[m][kt] = *(const bf16x8*)&A1[(m * 16 + l15) * 136 + kt * 32 + lq * 8];

    f32x4 acc2[2][2];
    #pragma unroll
    for (int i = 0; i < 2; ++i)
        #pragma unroll
        for (int m = 0; m < 2; ++m) acc2[i][m] = (f32x4){0.f, 0.f, 0.f, 0.f};

    for (int ch = 0; ch < 2; ++ch) {
        #pragma unroll
        for (int nt = 0; nt < 4; ++nt) {
            int lc0 = (w * 4 + nt) * 16;
            int g = ch * 256 + lc0 + l15;
            float bi = bin[g];
            f32x4 accp[2];
            __builtin_amdgcn_s_setprio(1);
            #pragma unroll
            for (int m = 0; m < 2; ++m) {
                f32x4 acc = {0.f, 0.f, 0.f, 0.f};
                #pragma unroll
                for (int kt = 0; kt < 4; ++kt) {
                    bf16x8 bB = *(const bf16x8*)(wb + OFF_D2WINT + (size_t)g * 128 + kt * 32 + lq * 8);
                    acc = __builtin_amdgcn_mfma_f32_16x16x32_bf16(aA[m][kt], bB, acc, 0, 0, 0);
                }
                accp[m] = acc;
            }
            __builtin_amdgcn_s_setprio(0);
            #pragma unroll
            for (int m = 0; m < 2; ++m)
                #pragma unroll
                for (int r = 0; r < 4; ++r)
                    Hd[(m * 16 + lq * 4 + r) * 264 + lc0 + l15] = (short)f2bf(gelu_f(accp[m][r] + bi));
        }
        __syncthreads();
        __builtin_amdgcn_s_setprio(1);
        #pragma unroll
        for (int kt = 0; kt < 8; ++kt) {
            bf16x8 a0 = *(const bf16x8*)&Hd[l15 * 264 + kt * 32 + lq * 8];
            bf16x8 a1 = *(const bf16x8*)&Hd[(16 + l15) * 264 + kt * 32 + lq * 8];
            bf16x8 b0 = *(const bf16x8*)(wb + OFF_D2WOUTT + (size_t)c0 * 512 + ch * 256 + kt * 32 + lq * 8);
            bf16x8 b1 = *(const bf16x8*)(wb + OFF_D2WOUTT + (size_t)c1 * 512 + ch * 256 + kt * 32 + lq * 8);
            acc2[0][0] = __builtin_amdgcn_mfma_f32_16x16x32_bf16(a0, b0, acc2[0][0], 0, 0, 0);
            acc2[0][1] = __builtin_amdgcn_mfma_f32_16x16x32_bf16(a1, b0, acc2[0][1], 0, 0, 0);
            acc2[1][0] = __builtin_amdgcn_mfma_f32_16x16x32_bf16(a0, b1, acc2[1][0], 0, 0, 0);
            acc2[1][1] = __builtin_amdgcn_mfma_f32_16x16x32_bf16(a1, b1, acc2[1][1], 0, 0, 0);
        }
        __builtin_amdgcn_s_setprio(0);
        __syncthreads();
    }
    // phase 11: xv += gelu(acc2 + bout)  (i = m*2 + ni)
    #pragma unroll
    for (int ni = 0; ni < 2; ++ni) {
        float bo = ni ? bo_1 : bo_0;
        #pragma unroll
        for (int m = 0; m < 2; ++m) {
            int i = m * 2 + ni;
            #pragma unroll
            for (int r = 0; r < 4; ++r)
                xv[i][r] += gelu_f(acc2[ni][m][r] + bo);
        }
    }

    // phase 12: LN4 stats + store
    {
        float s8[8], ss8[8];
        #pragma unroll
        for (int j = 0; j < 8; ++j) { s8[j] = 0.f; ss8[j] = 0.f; }
        #pragma unroll
        for (int i = 0; i < 4; ++i)
            #pragma unroll
            for (int r = 0; r < 4; ++r) {
                int j = (i >> 1) * 4 + r;
                float v = xv[i][r];
                s8[j] += v; ss8[j] += v * v;
            }
        #pragma unroll
        for (int m = 1; m < 16; m <<= 1)
            #pragma unroll
            for (int j = 0; j < 8; ++j) {
                s8[j] += __shfl_xor(s8[j], m);
                ss8[j] += __shfl_xor(ss8[j], m);
            }
        if (l15 == 0) {
            #pragma unroll
            for (int j = 0; j < 8; ++j) {
                int row = (j >> 2) * 16 + lq * 4 + (j & 3);
                pps[w * 32 + row] = s8[j];
                ppss[w * 32 + row] = ss8[j];
            }
        }
    }
    __syncthreads();
    if (t < 32) {
        float s = pps[t] + pps[32 + t] + pps[64 + t] + pps[96 + t];
        float ss = ppss[t] + ppss[32 + t] + ppss[64 + t] + ppss[96 + t];
        float mu = s * (1.f / 128.f);
        mu_[t] = mu;
        isd_[t] = 1.f / sqrtf(ss * (1.f / 128.f) - mu * mu + 1e-5f);
    }
    __syncthreads();
    #pragma unroll
    for (int i = 0; i < 4; ++i) {
        int m0 = (i >> 1) << 4, col = (i & 1) ? c1 : c0;
        float g = (i & 1) ? g4_1 : g4_0, bB = (i & 1) ? b4_1 : b4_0;
        #pragma unroll
        for (int r = 0; r < 4; ++r) {
            int row = m0 + lq * 4 + r;
            outE[(size_t)bn * 4096 + row * 128 + col] =
                g * (xv[i][r] - mu_[row]) * isd_[row] + bB;
        }
    }
}

extern "C" void kernel_launch(void* const* d_in, const int* in_sizes, int n_in,
                              void* d_out, int out_size, void* d_ws, size_t ws_size,
                              hipStream_t stream) {
    const float* hV     = (const float*)d_in[0];
    const float* hE     = (const float*)d_in[1];
    const float* hEV    = (const float*)d_in[2];
    const float* maskV  = (const float*)d_in[3];
    const float* maskA  = (const float*)d_in[4];
    const float* naWQ   = (const float*)d_in[5];
    const float* naWK   = (const float*)d_in[6];
    const float* naWV   = (const float*)d_in[7];
    const float* naWO   = (const float*)d_in[8];
    const float* eaWK   = (const float*)d_in[9];
    const float* eaWV   = (const float*)d_in[10];
    const float* eaWO   = (const float*)d_in[11];
    const float* d1Win  = (const float*)d_in[12];
    const float* d1bin  = (const float*)d_in[13];
    const float* d1Wout = (const float*)d_in[14];
    const float* d1bout = (const float*)d_in[15];
    const float* d2Win  = (const float*)d_in[16];
    const float* d2bin  = (const float*)d_in[17];
    const float* d2Wout = (const float*)d_in[18];
    const float* d2bout = (const float*)d_in[19];
    const float* opW1   = (const float*)d_in[20];
    const float* opb1   = (const float*)d_in[21];
    const float* opW2   = (const float*)d_in[22];
    const float* opb2   = (const float*)d_in[23];
    const float* opg    = (const float*)d_in[24];
    const float* opbeta = (const float*)d_in[25];
    const float* n1g    = (const float*)d_in[26];
    const float* n1b    = (const float*)d_in[27];
    const float* n3g    = (const float*)d_in[28];
    const float* n3b    = (const float*)d_in[29];
    const float* n4g    = (const float*)d_in[30];
    const float* n4b    = (const float*)d_in[31];
    const int*   Eidx   = (const int*)d_in[32];

    float* outV = (float*)d_out;
    float* outE = outV + (size_t)Bb * Nn * Hh;
    u16* xop = (u16*)d_ws;                        // [B*N*H] bf16 (2 MB)
    u16* wb  = (u16*)d_ws + (size_t)Bb * Nn * Hh; // bf16 weights (~880 KB)
    // scratch inside outE region (consumed before k_edge_fused writes it):
    u16* Qall = (u16*)(outE + (size_t)30 * 1048576);  // 2 MB @ +120MB
    u16* outr = (u16*)(outE + (size_t)31 * 1048576);  // 2 MB @ +124MB

    dim3 blk(256);
    k_prep<<<dim3(WB_TOTAL / 256), blk, 0, stream>>>(naWK, naWV, eaWK, eaWV, eaWO,
                                                     d2Win, d2Wout, opW2,
                                                     d1Win, d1Wout, opW1,
                                                     naWQ, naWO, wb);
    dim3 gridTok(Bb * Nn / 32);
    dim3 grid(Bb * Nn);
    k_qproj<<<gridTok, blk, 0, stream>>>(hV, wb, Qall);
    k_node_core<<<grid, blk, 0, stream>>>(hEV, maskA, Qall, wb, outr);
    k_node_post<<<gridTok, blk, 0, stream>>>(outr, hV, wb, maskV, n1g, n1b,
                                             d1bin, d1bout, opb1, opg, opbeta,
                                             outV, xop);
    k_edge_fused<<<grid, blk, 0, stream>>>(xop, hE, Eidx, maskA, wb, opb2,
                                           n3g, n3b, d2bin, d2bout, n4g, n4b,
                                           outE);
}

// Round 17
// 648.386 us; speedup vs baseline: 1.0057x; 1.0057x over previous
//
#include <hip/hip_runtime.h>
#include <hip/hip_bf16.h>
#include <math.h>

#define Bb 4
#define Nn 2048
#define Kk 32
#define Hh 128
#define NIi 256
#define NH_ 4
#define Dd 32
#define DFFh 512

#define NEGF -3.402823466e38f

typedef unsigned short u16;
typedef __attribute__((ext_vector_type(8))) short bf16x8;
typedef __attribute__((ext_vector_type(4))) short s16x4;
typedef __attribute__((ext_vector_type(4))) float f32x4;

// bf16 weight buffer offsets (elements); base = d_ws + 2MB
#define OFF_NAWKT   0        // [128][256]
#define OFF_NAWVT   32768    // [128][256]
#define OFF_EAWKT   65536    // [128][128]
#define OFF_EAWVT   81920
#define OFF_EAWOT   98304
#define OFF_D2WINT  114688   // [512][128]
#define OFF_D2WOUTT 180224   // [128][512]
#define OFF_OPW2T   245760   // [128][128]
#define OFF_D1WINT  262144   // [512][128]
#define OFF_D1WOUTT 327680   // [128][512]
#define OFF_OPW1T   393216   // [128][128]
#define OFF_NAWQT   409600   // [128][128]
#define OFF_NAWOT   425984   // [128][128]
#define WB_TOTAL    442368

// Fast exact-gelu: A&S 7.1.26 erf (|eps|<=1.5e-7), branchless.
__device__ __forceinline__ float gelu_f(float x) {
    float z = x * 0.7071067811865476f;
    float a = fabsf(z);
    float d = fmaf(0.3275911f, a, 1.0f);
    float t = __fdividef(1.0f, d);
    float p = fmaf(fmaf(fmaf(fmaf(1.061405429f, t, -1.453152027f), t,
                             1.421413741f), t, -0.284496736f), t, 0.254829592f);
    float e = __expf(-a * a);
    float erfa = fmaf(-p * t, e, 1.0f);
    float er = copysignf(erfa, z);
    return 0.5f * x * (1.0f + er);
}

__device__ __forceinline__ u16 f2bf(float f) {
    union { __hip_bfloat16 h; u16 u; } v;
    v.h = __float2bfloat16(f);
    return v.u;
}

__device__ __forceinline__ float bf2f(u16 u) {
    union { unsigned int u; float f; } v; v.u = ((unsigned int)u) << 16;
    return v.f;
}

__device__ __forceinline__ s16x4 packbf4(f32x4 v) {
    s16x4 r;
    r.x = (short)f2bf(v.x); r.y = (short)f2bf(v.y);
    r.z = (short)f2bf(v.z); r.w = (short)f2bf(v.w);
    return r;
}

// ---------------- K0: convert + transpose weights to bf16 in ws ---------------
__global__ __launch_bounds__(256) void k_prep(
    const float* __restrict__ naWK, const float* __restrict__ naWV,
    const float* __restrict__ eaWK, const float* __restrict__ eaWV,
    const float* __restrict__ eaWO, const float* __restrict__ d2Win,
    const float* __restrict__ d2Wout, const float* __restrict__ opW2,
    const float* __restrict__ d1Win, const float* __restrict__ d1Wout,
    const float* __restrict__ opW1, const float* __restrict__ naWQ,
    const float* __restrict__ naWO, u16* __restrict__ wb)
{
    int i = blockIdx.x * 256 + threadIdx.x;
    const float* src; int R, C, off;
    if (i < 32768)       { src = naWK;   R = 256; C = 128; off = OFF_NAWKT; }
    else if (i < 65536)  { src = naWV;   R = 256; C = 128; off = OFF_NAWVT; }
    else if (i < 81920)  { src = eaWK;   R = 128; C = 128; off = OFF_EAWKT; }
    else if (i < 98304)  { src = eaWV;   R = 128; C = 128; off = OFF_EAWVT; }
    else if (i < 114688) { src = eaWO;   R = 128; C = 128; off = OFF_EAWOT; }
    else if (i < 180224) { src = d2Win;  R = 128; C = 512; off = OFF_D2WINT; }
    else if (i < 245760) { src = d2Wout; R = 512; C = 128; off = OFF_D2WOUTT; }
    else if (i < 262144) { src = opW2;   R = 128; C = 128; off = OFF_OPW2T; }
    else if (i < 327680) { src = d1Win;  R = 128; C = 512; off = OFF_D1WINT; }
    else if (i < 393216) { src = d1Wout; R = 512; C = 128; off = OFF_D1WOUTT; }
    else if (i < 409600) { src = opW1;   R = 128; C = 128; off = OFF_OPW1T; }
    else if (i < 425984) { src = naWQ;   R = 128; C = 128; off = OFF_NAWQT; }
    else                 { src = naWO;   R = 128; C = 128; off = OFF_NAWOT; }
    int j = i - off;
    int c = j / R, r = j - c * R;       // dest W^T[C][R]
    wb[i] = f2bf(src[r * C + c]);
}

// ---------------- K1a: batched Qall = hV @ WQ (bf16) --------------------------
__global__ __launch_bounds__(256) void k_qproj(
    const float* __restrict__ hV, const u16* __restrict__ wb,
    u16* __restrict__ Qall)
{
    __shared__ __align__(16) short A1[32 * 136];
    const int bn = blockIdx.x, t = threadIdx.x;
    const int w = t >> 6, l = t & 63, l15 = l & 15, lq = l >> 4;
    const float* xp = hV + (size_t)bn * 4096;
    for (int i4 = t * 4; i4 < 4096; i4 += 1024)
        *(s16x4*)&A1[(i4 >> 7) * 136 + (i4 & 127)] = packbf4(*(const f32x4*)&xp[i4]);
    __syncthreads();
    #pragma unroll
    for (int ni = 0; ni < 2; ++ni) {
        int n0 = (w + 4 * ni) * 16;
        f32x4 acc0 = {0.f, 0.f, 0.f, 0.f}, acc1 = {0.f, 0.f, 0.f, 0.f};
        #pragma unroll
        for (int kt = 0; kt < 4; ++kt) {
            bf16x8 wf = *(const bf16x8*)(wb + OFF_NAWQT + (size_t)(n0 + l15) * 128 + kt * 32 + lq * 8);
            bf16x8 a0 = *(const bf16x8*)&A1[(l15) * 136 + kt * 32 + lq * 8];
            bf16x8 a1 = *(const bf16x8*)&A1[(16 + l15) * 136 + kt * 32 + lq * 8];
            acc0 = __builtin_amdgcn_mfma_f32_16x16x32_bf16(a0, wf, acc0, 0, 0, 0);
            acc1 = __builtin_amdgcn_mfma_f32_16x16x32_bf16(a1, wf, acc1, 0, 0, 0);
        }
        int col = n0 + l15;
        #pragma unroll
        for (int r = 0; r < 4; ++r) {
            Qall[(size_t)(bn * 32 + lq * 4 + r) * 128 + col] = f2bf(acc0[r]);
            Qall[(size_t)(bn * 32 + 16 + lq * 4 + r) * 128 + col] = f2bf(acc1[r]);
        }
    }
}

// ---------------- K1b: per-token attention core -> outr (bf16) ----------------
__global__ __launch_bounds__(256, 4) void k_node_core(
    const float* __restrict__ hEV, const float* __restrict__ maskA,
    const u16* __restrict__ Qall, const u16* __restrict__ wb,
    u16* __restrict__ outr)
{
    __shared__ __align__(16) short EVb[32 * 264];   // 16.9 KB
    __shared__ __align__(16) short KtT[128 * 36];   // K^T [h][k], 9.2 KB
    __shared__ __align__(16) short VtT[128 * 36];   // V^T [h][k], 9.2 KB
    __shared__ float Qs[128];
    __shared__ float att[NH_][Kk];

    const int bn = blockIdx.x, t = threadIdx.x;
    const int w = t >> 6, l = t & 63, l15 = l & 15, lq = l >> 4;
    const float* evp = hEV + (size_t)bn * 8192;
    for (int i8 = t * 8; i8 < 8192; i8 += 2048) {
        f32x4 v0 = *(const f32x4*)&evp[i8];
        f32x4 v1 = *(const f32x4*)&evp[i8 + 4];
        int r = i8 >> 8, c = i8 & 255;
        *(s16x4*)&EVb[r * 264 + c] = packbf4(v0);
        *(s16x4*)&EVb[r * 264 + c + 4] = packbf4(v1);
    }
    if (t < 128) Qs[t] = bf2f(Qall[(size_t)bn * 128 + t]);
    __syncthreads();

    // K = EV @ WK, V = EV @ WV; weight frag shared across both m-tiles
    #pragma unroll
    for (int i = 0; i < 4; ++i) {
        int pair = w + 4 * i;            // 0..15: mat = pair>>3, n = pair&7
        int mat = pair >> 3, n0 = (pair & 7) << 4;
        const u16* Bp = wb + (mat ? OFF_NAWVT : OFF_NAWKT);
        f32x4 acc0 = {0.f, 0.f, 0.f, 0.f}, acc1 = {0.f, 0.f, 0.f, 0.f};
        __builtin_amdgcn_s_setprio(1);
        #pragma unroll
        for (int kt = 0; kt < 8; ++kt) {
            bf16x8 wf = *(const bf16x8*)(Bp + (size_t)(n0 + l15) * 256 + kt * 32 + lq * 8);
            bf16x8 a0 = *(const bf16x8*)&EVb[(l15) * 264 + kt * 32 + lq * 8];
            bf16x8 a1 = *(const bf16x8*)&EVb[(16 + l15) * 264 + kt * 32 + lq * 8];
            acc0 = __builtin_amdgcn_mfma_f32_16x16x32_bf16(a0, wf, acc0, 0, 0, 0);
            acc1 = __builtin_amdgcn_mfma_f32_16x16x32_bf16(a1, wf, acc1, 0, 0, 0);
        }
        __builtin_amdgcn_s_setprio(0);
        int col = n0 + l15;
        short* dst = mat ? VtT : KtT;
        *(s16x4*)&dst[col * 36 + lq * 4] = packbf4(acc0);
        *(s16x4*)&dst[col * 36 + 16 + lq * 4] = packbf4(acc1);
    }
    __syncthreads();

    if (t < 128) {
        int nh = t >> 5, k = t & 31;
        float a = 0.f;
        #pragma unroll
        for (int d = 0; d < 32; ++d)
            a += Qs[nh * 32 + d] * bf2f(KtT[(nh * 32 + d) * 36 + k]);
        float mk = maskA[(size_t)bn * 32 + k];
        float lg = (mk > 0.f) ? a * 0.17677669529663687f : NEGF;
        float mx = lg;
        #pragma unroll
        for (int s = 16; s; s >>= 1) mx = fmaxf(mx, __shfl_xor(mx, s, 32));
        float e = __expf(lg - mx);
        float sum = e;
        #pragma unroll
        for (int s = 16; s; s >>= 1) sum += __shfl_xor(sum, s, 32);
        att[nh][k] = mk * e / sum;
    }
    __syncthreads();
    if (t < 128) {
        int nh = t >> 5, d = t & 31;
        float a = 0.f;
        #pragma unroll
        for (int k = 0; k < 32; ++k)
            a += att[nh][k] * bf2f(VtT[(nh * 32 + d) * 36 + k]);
        outr[(size_t)bn * 128 + t] = f2bf(a);
    }
}

// ---------------- K1c: fused node post: WO+LN1 -> FFN+LN1+mask -> LNop@W1 -----
__global__ __launch_bounds__(256, 3) void k_node_post(
    const u16* __restrict__ outr, const float* __restrict__ hV,
    const u16* __restrict__ wb, const float* __restrict__ maskV,
    const float* __restrict__ n1g, const float* __restrict__ n1b,
    const float* __restrict__ bin, const float* __restrict__ bout,
    const float* __restrict__ b1, const float* __restrict__ opg,
    const float* __restrict__ opb,
    float* __restrict__ outV, u16* __restrict__ xop)
{
    __shared__ __align__(16) float Xf[32][132];
    __shared__ __align__(16) short A1[32 * 136];
    __shared__ __align__(16) short Hd[32 * 264];
    __shared__ float mu_[32], isd_[32];
    const int bn = blockIdx.x, t = threadIdx.x;
    const int w = t >> 6, l = t & 63, l15 = l & 15, lq = l >> 4;
    const float* xp = hV + (size_t)bn * 4096;
    const u16* op = outr + (size_t)bn * 4096;
    for (int i4 = t * 4; i4 < 4096; i4 += 1024) {
        int r = i4 >> 7, c = i4 & 127;
        *(f32x4*)&Xf[r][c] = *(const f32x4*)&xp[i4];
        *(s16x4*)&A1[r * 136 + c] = *(const s16x4*)&op[i4];
    }
    __syncthreads();
    // WO gemm + gelu + residual (weight shared across both m-tiles)
    #pragma unroll
    for (int ni = 0; ni < 2; ++ni) {
        int n0 = (w + 4 * ni) * 16;
        f32x4 acc0 = {0.f, 0.f, 0.f, 0.f}, acc1 = {0.f, 0.f, 0.f, 0.f};
        #pragma unroll
        for (int kt = 0; kt < 4; ++kt) {
            bf16x8 wf = *(const bf16x8*)(wb + OFF_NAWOT + (size_t)(n0 + l15) * 128 + kt * 32 + lq * 8);
            bf16x8 a0 = *(const bf16x8*)&A1[(l15) * 136 + kt * 32 + lq * 8];
            bf16x8 a1 = *(const bf16x8*)&A1[(16 + l15) * 136 + kt * 32 + lq * 8];
            acc0 = __builtin_amdgcn_mfma_f32_16x16x32_bf16(a0, wf, acc0, 0, 0, 0);
            acc1 = __builtin_amdgcn_mfma_f32_16x16x32_bf16(a1, wf, acc1, 0, 0, 0);
        }
        int col = n0 + l15;
        #pragma unroll
        for (int r = 0; r < 4; ++r) {
            Xf[lq * 4 + r][col] += gelu_f(acc0[r]);
            Xf[16 + lq * 4 + r][col] += gelu_f(acc1[r]);
        }
    }
    __syncthreads();
    // LN1 stats
    {
        int r = t >> 3, sub = t & 7;
        float s = 0.f, ss = 0.f;
        #pragma unroll
        for (int j = 0; j < 16; ++j) { float v = Xf[r][sub * 16 + j]; s += v; ss += v * v; }
        #pragma unroll
        for (int m = 1; m < 8; m <<= 1) { s += __shfl_xor(s, m, 8); ss += __shfl_xor(ss, m, 8); }
        if (sub == 0) {
            float mu = s * (1.f / 128.f);
            mu_[r] = mu;
            isd_[r] = 1.f / sqrtf(ss * (1.f / 128.f) - mu * mu + 1e-5f);
        }
    }
    __syncthreads();
    // apply LN1 -> Xf fp32 + A1 bf16 (FFN input)
    for (int i4 = t * 4; i4 < 4096; i4 += 1024) {
        int r = i4 >> 7, c = i4 & 127;
        f32x4 xv = *(const f32x4*)&Xf[r][c];
        f32x4 y;
        #pragma unroll
        for (int j = 0; j < 4; ++j)
            y[j] = n1g[c + j] * (xv[j] - mu_[r]) * isd_[r] + n1b[c + j];
        *(f32x4*)&Xf[r][c] = y;
        *(s16x4*)&A1[r * 136 + c] = packbf4(y);
    }
    __syncthreads();

    // FFN
    bf16x8 aA[2][4];
    #pragma unroll
    for (int m = 0; m < 2; ++m)
        #pragma unroll
        for (int kt = 0; kt < 4; ++kt)
            aA[m][kt] = *(const bf16x8*)&A1[(m * 16 + l15) * 136 + kt * 32 + lq * 8];

    const int col0 = w * 16 + l15, col1 = (w + 4) * 16 + l15;
    f32x4 acc2[2][2];
    #pragma unroll
    for (int i = 0; i < 2; ++i)
        #pragma unroll
        for (int m = 0; m < 2; ++m) acc2[i][m] = (f32x4){0.f, 0.f, 0.f, 0.f};

    for (int ch = 0; ch < 2; ++ch) {
        #pragma unroll
        for (int nt = 0; nt < 4; ++nt) {
            int n0c = (w * 4 + nt) * 16;
            int g0 = ch * 256 + n0c;
            f32x4 bi4 = *(const f32x4*)&bin[g0 + lq * 4];
            f32x4 accp[2];
            #pragma unroll
            for (int m = 0; m < 2; ++m) {
                f32x4 acc = {0.f, 0.f, 0.f, 0.f};
                #pragma unroll
                for (int kt = 0; kt < 4; ++kt) {
                    bf16x8 wA = *(const bf16x8*)(wb + OFF_D1WINT + (size_t)(g0 + l15) * 128 + kt * 32 + lq * 8);
                    acc = __builtin_amdgcn_mfma_f32_16x16x32_bf16(wA, aA[m][kt], acc, 0, 0, 0);
                }
                accp[m] = acc;
            }
            #pragma unroll
            for (int m = 0; m < 2; ++m) {
                f32x4 g;
                #pragma unroll
                for (int r = 0; r < 4; ++r) g[r] = gelu_f(accp[m][r] + bi4[r]);
                *(s16x4*)&Hd[(m * 16 + l15) * 264 + n0c + lq * 4] = packbf4(g);
            }
        }
        __syncthreads();
        #pragma unroll
        for (int kt = 0; kt < 8; ++kt) {
            bf16x8 a0 = *(const bf16x8*)&Hd[l15 * 264 + kt * 32 + lq * 8];
            bf16x8 a1 = *(const bf16x8*)&Hd[(16 + l15) * 264 + kt * 32 + lq * 8];
            bf16x8 b0 = *(const bf16x8*)(wb + OFF_D1WOUTT + (size_t)col0 * 512 + ch * 256 + kt * 32 + lq * 8);
            bf16x8 b1 = *(const bf16x8*)(wb + OFF_D1WOUTT + (size_t)col1 * 512 + ch * 256 + kt * 32 + lq * 8);
            acc2[0][0] = __builtin_amdgcn_mfma_f32_16x16x32_bf16(a0, b0, acc2[0][0], 0, 0, 0);
            acc2[0][1] = __builtin_amdgcn_mfma_f32_16x16x32_bf16(a1, b0, acc2[0][1], 0, 0, 0);
            acc2[1][0] = __builtin_amdgcn_mfma_f32_16x16x32_bf16(a0, b1, acc2[1][0], 0, 0, 0);
            acc2[1][1] = __builtin_amdgcn_mfma_f32_16x16x32_bf16(a1, b1, acc2[1][1], 0, 0, 0);
        }
        __syncthreads();
    }
    #pragma unroll
    for (int ni = 0; ni < 2; ++ni) {
        int col = ni ? col1 : col0;
        float bo = bout[col];
        #pragma unroll
        for (int m = 0; m < 2; ++m)
            #pragma unroll
            for (int r = 0; r < 4; ++r)
                Xf[m * 16 + lq * 4 + r][col] += gelu_f(acc2[ni][m][r] + bo);
    }
    __syncthreads();
    // LN1 #2 stats
    {
        int r = t >> 3, sub = t & 7;
        float s = 0.f, ss = 0.f;
        #pragma unroll
        for (int j = 0; j < 16; ++j) { float v = Xf[r][sub * 16 + j]; s += v; ss += v * v; }
        #pragma unroll
        for (int m = 1; m < 8; m <<= 1) { s += __shfl_xor(s, m, 8); ss += __shfl_xor(ss, m, 8); }
        if (sub == 0) {
            float mu = s * (1.f / 128.f);
            mu_[r] = mu;
            isd_[r] = 1.f / sqrtf(ss * (1.f / 128.f) - mu * mu + 1e-5f);
        }
    }
    __syncthreads();
    // apply LN1 + mask -> outV global + Xf (becomes hv2)
    float* ov = outV + (size_t)bn * 4096;
    for (int i4 = t * 4; i4 < 4096; i4 += 1024) {
        int r = i4 >> 7, c = i4 & 127;
        float mv = maskV[bn * 32 + r];
        f32x4 xv = *(const f32x4*)&Xf[r][c];
        f32x4 o;
        #pragma unroll
        for (int j = 0; j < 4; ++j)
            o[j] = mv * (n1g[c + j] * (xv[j] - mu_[r]) * isd_[r] + n1b[c + j]);
        *(f32x4*)&Xf[r][c] = o;
        *(f32x4*)&ov[i4] = o;
    }
    __syncthreads();
    // LN op stats
    {
        int r = t >> 3, sub = t & 7;
        float s = 0.f, ss = 0.f;
        #pragma unroll
        for (int j = 0; j < 16; ++j) { float v = Xf[r][sub * 16 + j]; s += v; ss += v * v; }
        #pragma unroll
        for (int m = 1; m < 8; m <<= 1) { s += __shfl_xor(s, m, 8); ss += __shfl_xor(ss, m, 8); }
        if (sub == 0) {
            float mu = s * (1.f / 128.f);
            mu_[r] = mu;
            isd_[r] = 1.f / sqrtf(ss * (1.f / 128.f) - mu * mu + 1e-5f);
        }
    }
    __syncthreads();
    for (int i4 = t * 4; i4 < 4096; i4 += 1024) {
        int r = i4 >> 7, c = i4 & 127;
        f32x4 xv = *(const f32x4*)&Xf[r][c];
        f32x4 y;
        #pragma unroll
        for (int j = 0; j < 4; ++j)
            y[j] = opg[c + j] * (xv[j] - mu_[r]) * isd_[r] + opb[c + j];
        *(s16x4*)&A1[r * 136 + c] = packbf4(y);
    }
    __syncthreads();
    // W1 gemm -> xop bf16 (weight shared across both m-tiles)
    #pragma unroll
    for (int ni = 0; ni < 2; ++ni) {
        int n0 = (w + 4 * ni) * 16;
        f32x4 acc0 = {0.f, 0.f, 0.f, 0.f}, acc1 = {0.f, 0.f, 0.f, 0.f};
        #pragma unroll
        for (int kt = 0; kt < 4; ++kt) {
            bf16x8 wf = *(const bf16x8*)(wb + OFF_OPW1T + (size_t)(n0 + l15) * 128 + kt * 32 + lq * 8);
            bf16x8 a0 = *(const bf16x8*)&A1[(l15) * 136 + kt * 32 + lq * 8];
            bf16x8 a1 = *(const bf16x8*)&A1[(16 + l15) * 136 + kt * 32 + lq * 8];
            acc0 = __builtin_amdgcn_mfma_f32_16x16x32_bf16(a0, wf, acc0, 0, 0, 0);
            acc1 = __builtin_amdgcn_mfma_f32_16x16x32_bf16(a1, wf, acc1, 0, 0, 0);
        }
        int col = n0 + l15;
        float bb = b1[col];
        #pragma unroll
        for (int r = 0; r < 4; ++r) {
            xop[(size_t)(bn * 32 + lq * 4 + r) * 128 + col] = f2bf(acc0[r] + bb);
            xop[(size_t)(bn * 32 + 16 + lq * 4 + r) * 128 + col] = f2bf(acc1[r] + bb);
        }
    }
}

// ---------------- K4: fused edge pipeline (r16 edge kernel, unchanged) --------
#define LS_A 0
#define LS_B 9216
#define LS_C 17920
#define LS_D 26624
#define LS_SM 35840
__global__ __launch_bounds__(256, 4) void k_edge_fused(
    const u16* __restrict__ xop, const float* __restrict__ hE,
    const int* __restrict__ Eidx, const float* __restrict__ maskA,
    const u16* __restrict__ wb, const float* __restrict__ b2,
    const float* __restrict__ n3g, const float* __restrict__ n3b,
    const float* __restrict__ bin, const float* __restrict__ bout,
    const float* __restrict__ n4g, const float* __restrict__ n4b,
    float* __restrict__ outE)
{
    __shared__ __align__(16) char smem[37888];
    short* A1  = (short*)(smem + LS_A);
    short* Qe  = (short*)(smem + LS_B);
    short* Ke  = (short*)(smem + LS_C);
    short* Vp  = (short*)(smem + LS_D);
    short* Ls  = (short*)(smem + LS_A);        // bf16 logits/P [128][34]
    short* O2  = (short*)(smem + LS_B);        // attn out [32][136]
    short* Hd  = (short*)(smem + LS_B);        // FFN hidden [32][264]
    float* ms  = (float*)(smem + LS_SM);       // [32]
    float* mu_ = (float*)(smem + LS_SM + 128);
    float* isd_= (float*)(smem + LS_SM + 256);
    float* pps = (float*)(smem + LS_SM + 384); // [128]
    float* ppss= (float*)(smem + LS_SM + 896); // [128]
    float* xcf = (float*)(smem + LS_SM + 1408);// [128]
    int*   idxs= (int*)(smem + LS_SM + 1920);  // [32]

    const int bn = blockIdx.x, t = threadIdx.x;
    const int b = bn >> 11;
    const int w = t >> 6, l = t & 63, l15 = l & 15, lq = l >> 4;
    const int c0 = w * 16 + l15, c1 = c0 + 64;

    // phase 0: bases + per-col constants (hE loaded inline in phase 2a)
    if (t < 128) xcf[t] = bf2f(xop[(size_t)bn * 128 + t]);
    if (t < 32) { idxs[t] = Eidx[(size_t)bn * 32 + t]; ms[t] = maskA[(size_t)bn * 32 + t]; }
    const float bb_0 = b2[c0], bb_1 = b2[c1];
    const float g3_0 = n3g[c0], g3_1 = n3g[c1], b3_0 = n3b[c0], b3_1 = n3b[c1];
    const float g4_0 = n4g[c0], g4_1 = n4g[c1], b4_0 = n4b[c0], b4_1 = n4b[c1];
    const float bo_0 = bout[c0], bo_1 = bout[c1];
    __syncthreads();

    // phase 1: A = bf16(x ⊙ x[nbr])
    for (int i4 = t * 4; i4 < 4096; i4 += 1024) {
        int k = i4 >> 7, h = i4 & 127;
        s16x4 nb = *(const s16x4*)&xop[((size_t)b * Nn + idxs[k]) * 128 + h];
        f32x4 prod;
        prod.x = xcf[h] * bf2f(nb.x);
        prod.y = xcf[h + 1] * bf2f(nb.y);
        prod.z = xcf[h + 2] * bf2f(nb.z);
        prod.w = xcf[h + 3] * bf2f(nb.w);
        *(s16x4*)&A1[k * 136 + h] = packbf4(prod);
    }
    __syncthreads();

    // phase 2a: xv = hE + outer@W2 + b2  (weight shared across m; hE inline)
    float xv[4][4];
    #pragma unroll
    for (int ni = 0; ni < 2; ++ni) {
        int n0 = (w + 4 * ni) * 16;
        f32x4 acc0 = {0.f, 0.f, 0.f, 0.f}, acc1 = {0.f, 0.f, 0.f, 0.f};
        __builtin_amdgcn_s_setprio(1);
        #pragma unroll
        for (int kt = 0; kt < 4; ++kt) {
            bf16x8 wf = *(const bf16x8*)(wb + OFF_OPW2T + (size_t)(n0 + l15) * 128 + kt * 32 + lq * 8);
            bf16x8 a0 = *(const bf16x8*)&A1[(l15) * 136 + kt * 32 + lq * 8];
            bf16x8 a1 = *(const bf16x8*)&A1[(16 + l15) * 136 + kt * 32 + lq * 8];
            acc0 = __builtin_amdgcn_mfma_f32_16x16x32_bf16(a0, wf, acc0, 0, 0, 0);
            acc1 = __builtin_amdgcn_mfma_f32_16x16x32_bf16(a1, wf, acc1, 0, 0, 0);
        }
        __builtin_amdgcn_s_setprio(0);
        int col = n0 + l15;
        float bb = ni ? bb_1 : bb_0;
        #pragma unroll
        for (int r = 0; r < 4; ++r) {
            xv[ni][r] = acc0[r] + bb + hE[(size_t)bn * 4096 + (lq * 4 + r) * 128 + col];
            xv[2 + ni][r] = acc1[r] + bb + hE[(size_t)bn * 4096 + (16 + lq * 4 + r) * 128 + col];
        }
    }
    __syncthreads();
    // phase 2b: A = bf16(xv)   (xv[i]: i = (m-tile)*2 + ni)
    #pragma unroll
    for (int i = 0; i < 4; ++i) {
        int m0 = (i >> 1) << 4, col = (i & 1) ? c1 : c0;
        #pragma unroll
        for (int r = 0; r < 4; ++r)
            A1[(m0 + lq * 4 + r) * 136 + col] = (short)f2bf(xv[i][r]);
    }
    __syncthreads();

    // phase 3: projections Q=X@WO, K=X@WK, V=X@WV (weight shared across m;
    // operand-swapped so lane's 4 outputs are consecutive CHANNELS at one edge
    // row -> packed b64 Q/K writes)
    #pragma unroll
    for (int i = 0; i < 6; ++i) {
        int pair = w + 4 * i;            // 0..23: mat = pair>>3, n = pair&7
        int mat = pair >> 3, n0 = (pair & 7) << 4;
        const u16* Bp = wb + ((mat == 0) ? OFF_EAWOT : (mat == 1) ? OFF_EAWKT : OFF_EAWVT);
        f32x4 acc0 = {0.f, 0.f, 0.f, 0.f}, acc1 = {0.f, 0.f, 0.f, 0.f};
        __builtin_amdgcn_s_setprio(1);
        #pragma unroll
        for (int kt = 0; kt < 4; ++kt) {
            bf16x8 wf = *(const bf16x8*)(Bp + (size_t)(n0 + l15) * 128 + kt * 32 + lq * 8);
            bf16x8 a0 = *(const bf16x8*)&A1[(l15) * 136 + kt * 32 + lq * 8];
            bf16x8 a1 = *(const bf16x8*)&A1[(16 + l15) * 136 + kt * 32 + lq * 8];
            acc0 = __builtin_amdgcn_mfma_f32_16x16x32_bf16(wf, a0, acc0, 0, 0, 0);
            acc1 = __builtin_amdgcn_mfma_f32_16x16x32_bf16(wf, a1, acc1, 0, 0, 0);
        }
        __builtin_amdgcn_s_setprio(0);
        // acc0: rows(lq*4+r)=channels n0+lq*4+r, cols(l15)=edges 0-15
        // acc1: same channels, edges 16-31
        if (mat == 0) {
            *(s16x4*)&Qe[(l15) * 136 + n0 + lq * 4] = packbf4(acc0);
            *(s16x4*)&Qe[(16 + l15) * 136 + n0 + lq * 4] = packbf4(acc1);
        } else if (mat == 1) {
            *(s16x4*)&Ke[(l15) * 136 + n0 + lq * 4] = packbf4(acc0);
            *(s16x4*)&Ke[(16 + l15) * 136 + n0 + lq * 4] = packbf4(acc1);
        } else {
            #pragma unroll
            for (int r = 0; r < 4; ++r) {
                int ch = n0 + lq * 4 + r;
                int e0 = l15, e1 = 16 + l15;
                Vp[((e0 >> 3) * 32 + (ch & 31)) * 34 + (((e0 & 7) << 2) | (ch >> 5))] =
                    (short)f2bf(acc0[r]);
                Vp[((e1 >> 3) * 32 + (ch & 31)) * 34 + (((e1 & 7) << 2) | (ch >> 5))] =
                    (short)f2bf(acc1[r]);
            }
        }
    }
    __syncthreads();

    // phase 4: logits via MFMA, bf16 written in swapped order into Ls (A region)
    #pragma unroll
    for (int i = 0; i < 4; ++i) {
        int id = w + 4 * i;
        int h = id >> 2, rem = id & 3;
        int q0 = (rem >> 1) << 4, k0 = (rem & 1) << 4;
        int q = q0 + l15, k = k0 + l15;
        bf16x8 a = *(const bf16x8*)&Qe[(((h << 3) | (q >> 2)) * 136) + (((q & 3) << 5) + lq * 8)];
        bf16x8 bv = *(const bf16x8*)&Ke[(((h << 3) | (k >> 2)) * 136) + (((k & 3) << 5) + lq * 8)];
        f32x4 z = {0.f, 0.f, 0.f, 0.f};
        __builtin_amdgcn_s_setprio(1);
        f32x4 acc = __builtin_amdgcn_mfma_f32_16x16x32_bf16(a, bv, z, 0, 0, 0);
        __builtin_amdgcn_s_setprio(0);
        int aa = l15 & 3;
        int kq = (k0 >> 2) + (l15 >> 2);
        int cc = (h << 3) + (q0 >> 2) + lq;
        #pragma unroll
        for (int r = 0; r < 4; ++r) {
            int q2 = (r << 3) | kq;
            Ls[(aa * 32 + q2) * 34 + cc] = (short)f2bf(acc[r] * 0.17677669529663687f);
        }
    }
    __syncthreads();

    // phase 5: masked softmax over c, 256 threads (pair splits the 32-c row)
    {
        int rr = t >> 1, hf = t & 1;
        int q2 = rr & 31;
        float mq = ms[q2];
        float lv[16];
        int base = rr * 34 + hf * 16;
        #pragma unroll
        for (int j = 0; j < 4; ++j) {
            s16x4 v = *(const s16x4*)&Ls[base + j * 4];
            lv[j * 4] = bf2f(v.x); lv[j * 4 + 1] = bf2f(v.y);
            lv[j * 4 + 2] = bf2f(v.z); lv[j * 4 + 3] = bf2f(v.w);
        }
        float mx = NEGF;
        #pragma unroll
        for (int c = 0; c < 16; ++c) {
            lv[c] = (mq * ms[hf * 16 + c] > 0.f) ? lv[c] : NEGF;
            mx = fmaxf(mx, lv[c]);
        }
        mx = fmaxf(mx, __shfl_xor(mx, 1));
        float s = 0.f;
        #pragma unroll
        for (int c = 0; c < 16; ++c) { lv[c] = __expf(lv[c] - mx); s += lv[c]; }
        s += __shfl_xor(s, 1);
        float inv = 1.f / s;
        #pragma unroll
        for (int j = 0; j < 4; ++j) {
            f32x4 pv;
            pv.x = lv[j * 4] * inv; pv.y = lv[j * 4 + 1] * inv;
            pv.z = lv[j * 4 + 2] * inv; pv.w = lv[j * 4 + 3] * inv;
            *(s16x4*)&Ls[base + j * 4] = packbf4(pv);
        }
    }
    __syncthreads();

    // phase 6: PV (swapped) -> O2 packed b64 (stride 34)
    #pragma unroll
    for (int i = 0; i < 4; ++i) {
        int id = w + 4 * i;
        int a = id >> 2, rem = id & 3;
        int q0 = (rem >> 1) << 4, d0 = (rem & 1) << 4;
        bf16x8 pa = *(const bf16x8*)&Ls[((a * 32 + q0 + l15) * 34) + lq * 8];
        bf16x8 vb = *(const bf16x8*)&Vp[((a * 32 + d0 + l15) * 34) + lq * 8];
        f32x4 z = {0.f, 0.f, 0.f, 0.f};
        __builtin_amdgcn_s_setprio(1);
        f32x4 acc = __builtin_amdgcn_mfma_f32_16x16x32_bf16(vb, pa, z, 0, 0, 0);
        __builtin_amdgcn_s_setprio(0);
        *(s16x4*)&O2[(q0 + l15) * 136 + (a << 5) + d0 + lq * 4] = packbf4(acc);
    }
    __syncthreads();

    // phase 7: xv += gelu(O2 @ WO)  (weight shared across m)
    #pragma unroll
    for (int ni = 0; ni < 2; ++ni) {
        int n0 = (w + 4 * ni) * 16;
        f32x4 acc0 = {0.f, 0.f, 0.f, 0.f}, acc1 = {0.f, 0.f, 0.f, 0.f};
        __builtin_amdgcn_s_setprio(1);
        #pragma unroll
        for (int kt = 0; kt < 4; ++kt) {
            bf16x8 wf = *(const bf16x8*)(wb + OFF_EAWOT + (size_t)(n0 + l15) * 128 + kt * 32 + lq * 8);
            bf16x8 a0 = *(const bf16x8*)&O2[(l15) * 136 + kt * 32 + lq * 8];
            bf16x8 a1 = *(const bf16x8*)&O2[(16 + l15) * 136 + kt * 32 + lq * 8];
            acc0 = __builtin_amdgcn_mfma_f32_16x16x32_bf16(a0, wf, acc0, 0, 0, 0);
            acc1 = __builtin_amdgcn_mfma_f32_16x16x32_bf16(a1, wf, acc1, 0, 0, 0);
        }
        __builtin_amdgcn_s_setprio(0);
        #pragma unroll
        for (int r = 0; r < 4; ++r) {
            xv[ni][r] += gelu_f(acc0[r]);
            xv[2 + ni][r] += gelu_f(acc1[r]);
        }
    }
    __syncthreads();

    // phase 8: LN3 stats  (xv[i]: row block = (i>>1)*16, col = (i&1)?c1:c0)
    {
        float s8[8], ss8[8];
        #pragma unroll
        for (int j = 0; j < 8; ++j) { s8[j] = 0.f; ss8[j] = 0.f; }
        #pragma unroll
        for (int i = 0; i < 4; ++i)
            #pragma unroll
            for (int r = 0; r < 4; ++r) {
                int j = (i >> 1) * 4 + r;
                float v = xv[i][r];
                s8[j] += v; ss8[j] += v * v;
            }
        #pragma unroll
        for (int m = 1; m < 16; m <<= 1)
            #pragma unroll
            for (int j = 0; j < 8; ++j) {
                s8[j] += __shfl_xor(s8[j], m);
                ss8[j] += __shfl_xor(ss8[j], m);
            }
        if (l15 == 0) {
            #pragma unroll
            for (int j = 0; j < 8; ++j) {
                int row = (j >> 2) * 16 + lq * 4 + (j & 3);
                pps[w * 32 + row] = s8[j];
                ppss[w * 32 + row] = ss8[j];
            }
        }
    }
    __syncthreads();
    if (t < 32) {
        float s = pps[t] + pps[32 + t] + pps[64 + t] + pps[96 + t];
        float ss = ppss[t] + ppss[32 + t] + ppss[64 + t] + ppss[96 + t];
        float mu = s * (1.f / 128.f);
        mu_[t] = mu;
        isd_[t] = 1.f / sqrtf(ss * (1.f / 128.f) - mu * mu + 1e-5f);
    }
    __syncthreads();

    // phase 9: x2 = LN3(xv) -> regs + A region bf16 (Ls dead)
    #pragma unroll
    for (int i = 0; i < 4; ++i) {
        int m0 = (i >> 1) << 4, col = (i & 1) ? c1 : c0;
        float g = (i & 1) ? g3_1 : g3_0, bB = (i & 1) ? b3_1 : b3_0;
        #pragma unroll
        for (int r = 0; r < 4; ++r) {
            int row = m0 + lq * 4 + r;
            float v = g * (xv[i][r] - mu_[row]) * isd_[row] + bB;
            xv[i][r] = v;
            A1[row * 136 + col] = (short)f2bf(v);
        }
    }
    __syncthreads();

    // phase 10: FFN (Hd overlays B+C; weights already shared across m)
    bf16x8 aA[2][4];
    #pragma unroll
    for (int m = 0; m < 2; ++m)
        #pragma unroll
        for (int kt = 0; kt < 4; ++kt)
            aA[m][kt] = *(const bf16x8*)&A1[(m * 16 + l15) * 136 + kt * 32 + lq * 8];

    f32x4 acc2[2][2];
    #pragma unroll
    for (int i = 0; i < 2; ++i)
        #pragma unroll
        for (int m = 0; m < 2; ++m) acc2[i][m] = (f32x4){0.f, 0.f, 0.f, 0.f};

    for (int ch = 0; ch < 2; ++ch) {
        #pragma unroll
        for (int nt = 0; nt < 4; ++nt) {
            int lc0 = (w * 4 + nt) * 16;
            int g = ch * 256 + lc0 + l15;
            float bi = bin[g];
            f32x4 accp[2];
            __builtin_amdgcn_s_setprio(1);
            #pragma unroll
            for (int m = 0; m < 2; ++m) {
                f32x4 acc = {0.f, 0.f, 0.f, 0.f};
                #pragma unroll
                for (int kt = 0; kt < 4; ++kt) {
                    bf16x8 bB = *(const bf16x8*)(wb + OFF_D2WINT + (size_t)g * 128 + kt * 32 + lq * 8);
                    acc = __builtin_amdgcn_mfma_f32_16x16x32_bf16(aA[m][kt], bB, acc, 0, 0, 0);
                }
                accp[m] = acc;
            }
            __builtin_amdgcn_s_setprio(0);
            #pragma unroll
            for (int m = 0; m < 2; ++m)
                #pragma unroll
                for (int r = 0; r < 4; ++r)
                    Hd[(m * 16 + lq * 4 + r) * 264 + lc0 + l15] = (short)f2bf(gelu_f(accp[m][r] + bi));
        }
        __syncthreads();
        __builtin_amdgcn_s_setprio(1);
        #pragma unroll
        for (int kt = 0; kt < 8; ++kt) {
            bf16x8 a0 = *(const bf16x8*)&Hd[l15 * 264 + kt * 32 + lq * 8];
            bf16x8 a1 = *(const bf16x8*)&Hd[(16 + l15) * 264 + kt * 32 + lq * 8];
            bf16x8 b0 = *(const bf16x8*)(wb + OFF_D2WOUTT + (size_t)c0 * 512 + ch * 256 + kt * 32 + lq * 8);
            bf16x8 b1 = *(const bf16x8*)(wb + OFF_D2WOUTT + (size_t)c1 * 512 + ch * 256 + kt * 32 + lq * 8);
            acc2[0][0] = __builtin_amdgcn_mfma_f32_16x16x32_bf16(a0, b0, acc2[0][0], 0, 0, 0);
            acc2[0][1] = __builtin_amdgcn_mfma_f32_16x16x32_bf16(a1, b0, acc2[0][1], 0, 0, 0);
            acc2[1][0] = __builtin_amdgcn_mfma_f32_16x16x32_bf16(a0, b1, acc2[1][0], 0, 0, 0);
            acc2[1][1] = __builtin_amdgcn_mfma_f32_16x16x32_bf16(a1, b1, acc2[1][1], 0, 0, 0);
        }
        __builtin_amdgcn_s_setprio(0);
        __syncthreads();
    }
    // phase 11: xv += gelu(acc2 + bout)  (i = m*2 + ni)
    #pragma unroll
    for (int ni = 0; ni < 2; ++ni) {
        float bo = ni ? bo_1 : bo_0;
        #pragma unroll
        for (int m = 0; m < 2; ++m) {
            int i = m * 2 + ni;
            #pragma unroll
            for (int r = 0; r < 4; ++r)
                xv[i][r] += gelu_f(acc2[ni][m][r] + bo);
        }
    }

    // phase 12: LN4 stats + store
    {
        float s8[8], ss8[8];
        #pragma unroll
        for (int j = 0; j < 8; ++j) { s8[j] = 0.f; ss8[j] = 0.f; }
        #pragma unroll
        for (int i = 0; i < 4; ++i)
            #pragma unroll
            for (int r = 0; r < 4; ++r) {
                int j = (i >> 1) * 4 + r;
                float v = xv[i][r];
                s8[j] += v; ss8[j] += v * v;
            }
        #pragma unroll
        for (int m = 1; m < 16; m <<= 1)
            #pragma unroll
            for (int j = 0; j < 8; ++j) {
                s8[j] += __shfl_xor(s8[j], m);
                ss8[j] += __shfl_xor(ss8[j], m);
            }
        if (l15 == 0) {
            #pragma unroll
            for (int j = 0; j < 8; ++j) {
                int row = (j >> 2) * 16 + lq * 4 + (j & 3);
                pps[w * 32 + row] = s8[j];
                ppss[w * 32 + row] = ss8[j];
            }
        }
    }
    __syncthreads();
    if (t < 32) {
        float s = pps[t] + pps[32 + t] + pps[64 + t] + pps[96 + t];
        float ss = ppss[t] + ppss[32 + t] + ppss[64 + t] + ppss[96 + t];
        float mu = s * (1.f / 128.f);
        mu_[t] = mu;
        isd_[t] = 1.f / sqrtf(ss * (1.f / 128.f) - mu * mu + 1e-5f);
    }
    __syncthreads();
    #pragma unroll
    for (int i = 0; i < 4; ++i) {
        int m0 = (i >> 1) << 4, col = (i & 1) ? c1 : c0;
        float g = (i & 1) ? g4_1 : g4_0, bB = (i & 1) ? b4_1 : b4_0;
        #pragma unroll
        for (int r = 0; r < 4; ++r) {
            int row = m0 + lq * 4 + r;
            outE[(size_t)bn * 4096 + row * 128 + col] =
                g * (xv[i][r] - mu_[row]) * isd_[row] + bB;
        }
    }
}

extern "C" void kernel_launch(void* const* d_in, const int* in_sizes, int n_in,
                              void* d_out, int out_size, void* d_ws, size_t ws_size,
                              hipStream_t stream) {
    const float* hV     = (const float*)d_in[0];
    const float* hE     = (const float*)d_in[1];
    const float* hEV    = (const float*)d_in[2];
    const float* maskV  = (const float*)d_in[3];
    const float* maskA  = (const float*)d_in[4];
    const float* naWQ   = (const float*)d_in[5];
    const float* naWK   = (const float*)d_in[6];
    const float* naWV   = (const float*)d_in[7];
    const float* naWO   = (const float*)d_in[8];
    const float* eaWK   = (const float*)d_in[9];
    const float* eaWV   = (const float*)d_in[10];
    const float* eaWO   = (const float*)d_in[11];
    const float* d1Win  = (const float*)d_in[12];
    const float* d1bin  = (const float*)d_in[13];
    const float* d1Wout = (const float*)d_in[14];
    const float* d1bout = (const float*)d_in[15];
    const float* d2Win  = (const float*)d_in[16];
    const float* d2bin  = (const float*)d_in[17];
    const float* d2Wout = (const float*)d_in[18];
    const float* d2bout = (const float*)d_in[19];
    const float* opW1   = (const float*)d_in[20];
    const float* opb1   = (const float*)d_in[21];
    const float* opW2   = (const float*)d_in[22];
    const float* opb2   = (const float*)d_in[23];
    const float* opg    = (const float*)d_in[24];
    const float* opbeta = (const float*)d_in[25];
    const float* n1g    = (const float*)d_in[26];
    const float* n1b    = (const float*)d_in[27];
    const float* n3g    = (const float*)d_in[28];
    const float* n3b    = (const float*)d_in[29];
    const float* n4g    = (const float*)d_in[30];
    const float* n4b    = (const float*)d_in[31];
    const int*   Eidx   = (const int*)d_in[32];

    float* outV = (float*)d_out;
    float* outE = outV + (size_t)Bb * Nn * Hh;
    u16* xop = (u16*)d_ws;                        // [B*N*H] bf16 (2 MB)
    u16* wb  = (u16*)d_ws + (size_t)Bb * Nn * Hh; // bf16 weights (~880 KB)
    // scratch inside outE region (consumed before k_edge_fused writes it):
    u16* Qall = (u16*)(outE + (size_t)30 * 1048576);  // 2 MB @ +120MB
    u16* outr = (u16*)(outE + (size_t)31 * 1048576);  // 2 MB @ +124MB

    dim3 blk(256);
    k_prep<<<dim3(WB_TOTAL / 256), blk, 0, stream>>>(naWK, naWV, eaWK, eaWV, eaWO,
                                                     d2Win, d2Wout, opW2,
                                                     d1Win, d1Wout, opW1,
                                                     naWQ, naWO, wb);
    dim3 gridTok(Bb * Nn / 32);
    dim3 grid(Bb * Nn);
    k_qproj<<<gridTok, blk, 0, stream>>>(hV, wb, Qall);
    k_node_core<<<grid, blk, 0, stream>>>(hEV, maskA, Qall, wb, outr);
    k_node_post<<<gridTok, blk, 0, stream>>>(outr, hV, wb, maskV, n1g, n1b,
                                             d1bin, d1bout, opb1, opg, opbeta,
                                             outV, xop);
    k_edge_fused<<<grid, blk, 0, stream>>>(xop, hE, Eidx, maskA, wb, opb2,
                                           n3g, n3b, d2bin, d2bout, n4g, n4b,
                                           outE);
}